// Round 8
// baseline (7692.805 us; speedup 1.0000x reference)
//
#include <hip/hip_runtime.h>
#include <hip/hip_bf16.h>

typedef __bf16 bf16;
typedef __bf16 bf16x8 __attribute__((ext_vector_type(8)));
typedef float f32x4 __attribute__((ext_vector_type(4)));

#define N_ROWS   512      // rows 0..255 seq1, 256..511 seq2
#define HID      1024
#define KX       320      // EMB=300 padded to 320
#define KTOT     1344     // 320 + 1024
#define NSTEPS   128
#define EMB_D    300
#define HC_W     3332     // 1025+1025+1+1025+256

// workspace layout (bytes)
#define WBT_OFF   0UL          // bf16 [4096][1344]  (packed, transposed)
#define XB_OFF    11010048UL   // bf16 [128][512][320]
#define HB_OFF    52953088UL   // bf16 [2][512][1024]
#define BIASP_OFF 55050240UL   // f32  [4096] (packed order)
#define HC_OFF    55066624UL   // f32  [256][3332]
#define H2T_OFF   58478592UL   // f32  [1025][256]
#define T1_OFF    59528192UL   // f32  [256][1025]
#define E1_OFF    60577792UL   // f32  [256][512]
#define BAR_OFF   61102080UL   // u32: 8 monotonic lines, 64B stride (lockstep barrier)

__device__ __forceinline__ float sigm(float x) { return 1.f / (1.f + __expf(-x)); }
__device__ __forceinline__ float tanh_fast(float x) {
  float xc = fminf(fmaxf(x, -15.f), 15.f);
  float e = __expf(2.f * xc);
  return (e - 1.f) / (e + 1.f);
}

// ---- pack kernels (r2-proven versions) ----------------------------------
// packed gate-col order: p = cbk*128 + g*32 + c  <->  orig col g*1024 + cbk*32 + c
__global__ void pack_wbt(const float* __restrict__ lk, bf16* __restrict__ wbt) {
  int p = blockIdx.x * 256 + threadIdx.x;   // 0..4095
  int k = blockIdx.y;                        // 0..1343
  int cbk = p >> 7, g = (p >> 5) & 3, c = p & 31;
  int oc = g * HID + cbk * 32 + c;
  float v = 0.f;
  if (k < KX) { if (k < EMB_D) v = lk[(size_t)k * 4096 + oc]; }
  else v = lk[(size_t)(EMB_D + k - KX) * 4096 + oc];
  wbt[(size_t)p * KTOT + k] = (bf16)v;
}

__global__ void pack_xb(const int* __restrict__ in1, const int* __restrict__ in2,
                        const float* __restrict__ emb, bf16* __restrict__ xb) {
  int idx = blockIdx.x * 256 + threadIdx.x;  // < 128*512*320
  int e = idx % 320;
  int rt = idx / 320;
  int r = rt & 511;
  int t = rt >> 9;
  int tok = (r < 256) ? in1[r * 128 + t] : in2[(r - 256) * 128 + t];
  float v = (e < EMB_D) ? emb[(size_t)tok * EMB_D + e] : 0.f;
  xb[(size_t)idx] = (bf16)v;
}

__global__ void pack_misc(const float* __restrict__ h1i, const float* __restrict__ h2i,
                          const float* __restrict__ bias, bf16* __restrict__ hb0,
                          float* __restrict__ biasp, unsigned* __restrict__ bar) {
  int idx = blockIdx.x * 256 + threadIdx.x;
  if (idx < N_ROWS * HID) {
    int r = idx >> 10, k = idx & 1023;
    float v = (r < 256) ? h1i[(size_t)r * HID + k] : h2i[(size_t)(r - 256) * HID + k];
    hb0[idx] = (bf16)v;
  }
  if (idx < 4096) {
    int cbk = idx >> 7, g = (idx >> 5) & 3, c = idx & 31;
    biasp[idx] = bias[g * HID + cbk * 32 + c];
  }
  if (idx < 512) bar[idx] = 0u;   // reset barrier lines every launch
}

// ---- cooperative LSTM recurrence ---------------------------------------
// grid 256 = 8 row-blocks x 32 cell-col-blocks (r6-proven mapping; under
// round-robin bid->XCD each XCD hosts 4 distinct cbk -> 1.4MB weight set).
// wave w owns rows w*16..w*16+15, ALL 128 packed cols (no gate exchange):
//   acc[ni][q] = G[row=w*16+(lane>>4)*4+q][pcol=ni*16+(lane&15)], g=ni>>1
// Double-buffered As/Bs, 1 __syncthreads/chunk; 2 reg slot sets -> loads
// issued 3 chunks ahead, ds_write 1 chunk ahead (2-iter latency cover).
// GLOBAL lockstep barrier (preserves L2 weight sharing): arrivals spread
// over 8 monotonic lines (bid&7, 64B apart, 32 arrivals each); tid==0
// polls all 8 lines >= 32*t, acquire each (RMW release sequences), bcast
// via __syncthreads. Wait at kc==2, just before first h-load issue (nkc=5).
struct Slot { bf16x8 a0, a1, b[4]; };

__launch_bounds__(256, 2)
__global__ void lstm_coop(const bf16* __restrict__ xb, const bf16* __restrict__ wbt,
                          bf16* __restrict__ hb, const float* __restrict__ biasp,
                          const float* __restrict__ c1i, const float* __restrict__ c2i,
                          const int* __restrict__ s1, const int* __restrict__ s2,
                          unsigned* __restrict__ bar) {
  __shared__ bf16 As[2][64][64];     // 16 KB, XOR-swizzled 16B chunks
  __shared__ bf16 Bs[2][128][64];    // 32 KB
  const int tid = threadIdx.x;
  const int wave = tid >> 6;
  const int lane = tid & 63;
  const int lrow = lane & 15;
  const int hi = lane >> 4;        // 0..3
  const int l7 = lane & 7;
  const int bid = blockIdx.x;
  const int rb = bid >> 5;
  const int cbk = bid & 31;
  const int r0 = rb * 64;

  const int rowbase = r0 + wave * 16 + hi * 4;   // + q (q=0..3)
  const int cell0 = cbk * 32 + lrow;             // + 16*e (e=0..1)

  int slen[4];
#pragma unroll
  for (int q = 0; q < 4; ++q) {
    int rr = rowbase + q;
    slen[q] = (rr < 256) ? s1[rr] : s2[rr - 256];
  }

  float creg[2][4];   // [e][q], stays f32 in registers
  {
    const float* cb = (rowbase < 256) ? c1i : c2i;
    const int radj = (rowbase < 256) ? rowbase : rowbase - 256;
#pragma unroll
    for (int e = 0; e < 2; ++e)
#pragma unroll
      for (int q = 0; q < 4; ++q)
        creg[e][q] = cb[(size_t)(radj + q) * HID + cell0 + e * 16];
  }

  // bias folded into accumulator init: acc[ni] col = ni*16+lrow (col-only dep)
  float bv[8];
#pragma unroll
  for (int ni = 0; ni < 8; ++ni)
    bv[ni] = biasp[cbk * 128 + ni * 16 + lrow];

  const bf16* wsrc = wbt + (size_t)(cbk * 128) * KTOT;

  // staging thread mapping (r2-proven swizzles)
  const int a_r = tid >> 2, a_c = tid & 3;
  const int b_r8 = tid >> 3, b_c = tid & 7;
  const int asw0 = ((a_c       ^ (a_r & 7)) << 3);
  const int asw1 = (((a_c + 4) ^ (a_r & 7)) << 3);
  const int bsw  = ((b_c ^ (b_r8 & 7)) << 3);     // +32q keeps row&7 constant

  Slot sl[2];
  auto issue_loads = [&](int nt, int nkc, Slot& s) {
    const bf16* asrc = (nkc < 5)
        ? (xb + ((size_t)nt * N_ROWS + r0 + a_r) * KX + nkc * 64 + a_c * 8)
        : (hb + ((size_t)(nt & 1) << 19) + ((size_t)(r0 + a_r) << 10) +
           (nkc * 64 - KX) + a_c * 8);
    s.a0 = *reinterpret_cast<const bf16x8*>(asrc);
    s.a1 = *reinterpret_cast<const bf16x8*>(asrc + 32);
    const bf16* bsrc = wsrc + (size_t)b_r8 * KTOT + nkc * 64 + b_c * 8;
#pragma unroll
    for (int q = 0; q < 4; ++q)
      s.b[q] = *reinterpret_cast<const bf16x8*>(bsrc + (size_t)(32 * q) * KTOT);
  };

  // prologue: buf0 <- chunk 0 (t=0, x); slot1 <- chunk 1; slot0 <- chunk 2
  issue_loads(0, 0, sl[0]);
  *reinterpret_cast<bf16x8*>(&As[0][a_r][asw0]) = sl[0].a0;
  *reinterpret_cast<bf16x8*>(&As[0][a_r][asw1]) = sl[0].a1;
#pragma unroll
  for (int q = 0; q < 4; ++q)
    *reinterpret_cast<bf16x8*>(&Bs[0][b_r8 + 32 * q][bsw]) = sl[0].b[q];
  issue_loads(0, 1, sl[1]);
  issue_loads(0, 2, sl[0]);
  __syncthreads();
  int db = 0;

  unsigned* mycnt = bar + (bid & 7) * 16;   // 64B-spaced monotonic line

  for (int t = 0; t < NSTEPS; ++t) {
    f32x4 acc[8];
#pragma unroll
    for (int ni = 0; ni < 8; ++ni)
      acc[ni] = f32x4{bv[ni], bv[ni], bv[ni], bv[ni]};

    // iter KC: ds_write chunk KC+1 from slot (KC+1)&1; refill slot with
    // chunk KC+3 (wraps to next step's x chunks); compute chunk KC.
    // Cross-step slot-parity swap makes steps process chunks in order
    // 0,2,1,3,4..20 -- order-invariant accumulation, correctness-proven (r7).
#define CHUNK(KC)                                                              \
    {                                                                          \
      constexpr int S = ((KC) + 1) & 1;                                        \
      *reinterpret_cast<bf16x8*>(&As[db ^ 1][a_r][asw0]) = sl[S].a0;           \
      *reinterpret_cast<bf16x8*>(&As[db ^ 1][a_r][asw1]) = sl[S].a1;           \
      _Pragma("unroll")                                                        \
      for (int q = 0; q < 4; ++q)                                              \
        *reinterpret_cast<bf16x8*>(&Bs[db ^ 1][b_r8 + 32 * q][bsw]) = sl[S].b[q]; \
      if constexpr ((KC) == 2) {                                               \
        if (t > 0) {                                                           \
          if (tid == 0) {                                                      \
            const unsigned tgt = 32u * (unsigned)t;                            \
            _Pragma("unroll")                                                  \
            for (int g = 0; g < 8; ++g) {                                      \
              const unsigned* ln = bar + g * 16;                               \
              while (__hip_atomic_load(ln, __ATOMIC_RELAXED,                   \
                                       __HIP_MEMORY_SCOPE_AGENT) < tgt)        \
                __builtin_amdgcn_s_sleep(2);                                   \
              (void)__hip_atomic_load(ln, __ATOMIC_ACQUIRE,                    \
                                      __HIP_MEMORY_SCOPE_AGENT);               \
            }                                                                  \
          }                                                                    \
          __syncthreads();                                                     \
        }                                                                      \
      }                                                                        \
      {                                                                        \
        constexpr int NK = ((KC) >= 18) ? ((KC) + 3 - 21) : ((KC) + 3);        \
        const int nt = ((KC) >= 18) ? (t + 1) : t;                             \
        if (nt < NSTEPS) issue_loads(nt, NK, sl[S]);                           \
      }                                                                        \
      _Pragma("unroll")                                                        \
      for (int ks = 0; ks < 2; ++ks) {                                         \
        const int cs = (((ks << 2) | hi) ^ l7) << 3;                           \
        bf16x8 af = *reinterpret_cast<const bf16x8*>(&As[db][wave * 16 + lrow][cs]); \
        _Pragma("unroll")                                                      \
        for (int ni = 0; ni < 8; ++ni) {                                       \
          bf16x8 bfv = *reinterpret_cast<const bf16x8*>(&Bs[db][ni * 16 + lrow][cs]); \
          acc[ni] = __builtin_amdgcn_mfma_f32_16x16x32_bf16(af, bfv, acc[ni], 0, 0, 0); \
        }                                                                      \
      }                                                                        \
      __syncthreads();                                                         \
      db ^= 1;                                                                 \
    }

    CHUNK(0)  CHUNK(1)  CHUNK(2)  CHUNK(3)  CHUNK(4)  CHUNK(5)  CHUNK(6)
    CHUNK(7)  CHUNK(8)  CHUNK(9)  CHUNK(10) CHUNK(11) CHUNK(12) CHUNK(13)
    CHUNK(14) CHUNK(15) CHUNK(16) CHUNK(17) CHUNK(18) CHUNK(19) CHUNK(20)
#undef CHUNK

    // cell update: fully in-register (g = ni>>1, cc = (ni&1)*16 + lrow)
    {
      const size_t curo = (size_t)(t & 1) << 19;
      const bf16* hc = hb + curo;
      bf16* hnb = hb + (curo ^ ((size_t)1 << 19));
#pragma unroll
      for (int e = 0; e < 2; ++e)
#pragma unroll
        for (int q = 0; q < 4; ++q) {
          float ig = acc[0 + e][q];
          float jg = acc[2 + e][q];
          float fg = acc[4 + e][q];
          float og = acc[6 + e][q];
          float cn = sigm(fg + 1.f) * creg[e][q] + sigm(ig) * tanh_fast(jg);
          float hv = tanh_fast(cn) * sigm(og);
          size_t off = ((size_t)(rowbase + q) << 10) + cell0 + e * 16;
          float ho;
          if (t < slen[q]) { creg[e][q] = cn; ho = hv; }
          else ho = (float)hc[off];
          hnb[off] = (bf16)ho;
        }
    }

    // arrive: drain h stores (syncthreads emits vmcnt(0)) then release-RMW
    __syncthreads();
    if (t < NSTEPS - 1 && tid == 0)
      __hip_atomic_fetch_add(mycnt, 1u, __ATOMIC_ACQ_REL, __HIP_MEMORY_SCOPE_AGENT);
  }
}

// ---- head ---------------------------------------------------------------
__global__ void feat_kernel(const bf16* __restrict__ hb0, const int* __restrict__ s1,
                            const int* __restrict__ s2, float* __restrict__ HC,
                            float* __restrict__ H2T) {
  int a = blockIdx.x;
  int tid = threadIdx.x;
  __shared__ float red[256];
  const bf16* h1r = hb0 + (size_t)a * HID;
  const bf16* h2r = hb0 + (size_t)(a + 256) * HID;
  float l1 = (float)s1[a] * (1.f / 128.f);
  float l2 = (float)s2[a] * (1.f / 128.f);
  float dacc = 0.f;
  for (int k = tid; k < 1025; k += 256) {
    float v1 = (k < HID) ? (float)h1r[k] : l1;
    float v2 = (k < HID) ? (float)h2r[k] : l2;
    HC[(size_t)a * HC_W + k] = v1;
    HC[(size_t)a * HC_W + 1025 + k] = v2;
    HC[(size_t)a * HC_W + 2051 + k] = v1 * v2;
    H2T[(size_t)k * 256 + a] = v2;
    float d = v1 - v2;
    dacc += d * d;
  }
  red[tid] = dacc;
  __syncthreads();
  for (int s = 128; s > 0; s >>= 1) {
    if (tid < s) red[tid] += red[tid + s];
    __syncthreads();
  }
  if (tid == 0) HC[(size_t)a * HC_W + 2050] = red[0];
}

__global__ void t1_kernel(const float* __restrict__ HC, const float* __restrict__ Wh,
                          float* __restrict__ T1) {
  int j = blockIdx.x * 256 + threadIdx.x;
  int a0 = blockIdx.y * 32;
  __shared__ float sh[32][64];
  float acc[32];
#pragma unroll
  for (int r = 0; r < 32; ++r) acc[r] = 0.f;
  for (int kc = 0; kc < 1025; kc += 64) {
    int kn = (1025 - kc < 64) ? (1025 - kc) : 64;
    for (int idx = threadIdx.x; idx < 2048; idx += 256) {
      int r = idx >> 6, kk = idx & 63;
      sh[r][kk] = (kk < kn) ? HC[(size_t)(a0 + r) * HC_W + kc + kk] : 0.f;
    }
    __syncthreads();
    if (j < 1025) {
      for (int kk = 0; kk < kn; ++kk) {
        float w = Wh[(size_t)(kc + kk) * 1025 + j];
#pragma unroll
        for (int r = 0; r < 32; ++r) acc[r] += sh[r][kk] * w;
      }
    }
    __syncthreads();
  }
  if (j < 1025) {
    for (int r = 0; r < 32; ++r) T1[(size_t)(a0 + r) * 1025 + j] = acc[r];
  }
}

__global__ void inter_kernel(const float* __restrict__ T1, const float* __restrict__ H2T,
                             float* __restrict__ HC) {
  int a0 = blockIdx.x * 8;
  int b = threadIdx.x;
  __shared__ float sT[8][1025];
  for (int idx = threadIdx.x; idx < 8 * 1025; idx += 256) {
    int r = idx / 1025, k = idx - r * 1025;
    sT[r][k] = T1[(size_t)(a0 + r) * 1025 + k];
  }
  __syncthreads();
  float acc[8];
#pragma unroll
  for (int r = 0; r < 8; ++r) acc[r] = 0.f;
  for (int k = 0; k < 1025; ++k) {
    float v = H2T[(size_t)k * 256 + b];
#pragma unroll
    for (int r = 0; r < 8; ++r) acc[r] += sT[r][k] * v;
  }
#pragma unroll
  for (int r = 0; r < 8; ++r)
    HC[(size_t)(a0 + r) * HC_W + 3076 + b] = acc[r];
}

__global__ void e1_kernel(const float* __restrict__ HC, const float* __restrict__ W1,
                          const float* __restrict__ b1, float* __restrict__ E1) {
  int a0 = blockIdx.x * 8;
  int j = blockIdx.y * 256 + threadIdx.x;
  __shared__ float sh[8][128];
  float acc[8];
#pragma unroll
  for (int r = 0; r < 8; ++r) acc[r] = 0.f;
  for (int kc = 0; kc < HC_W; kc += 128) {
    int kn = (HC_W - kc < 128) ? (HC_W - kc) : 128;
    for (int idx = threadIdx.x; idx < 1024; idx += 256) {
      int r = idx >> 7, kk = idx & 127;
      sh[r][kk] = (kk < kn) ? HC[(size_t)(a0 + r) * HC_W + kc + kk] : 0.f;
    }
    __syncthreads();
    for (int kk = 0; kk < kn; ++kk) {
      float w = W1[(size_t)(kc + kk) * 512 + j];
#pragma unroll
      for (int r = 0; r < 8; ++r) acc[r] += sh[r][kk] * w;
    }
    __syncthreads();
  }
  float bj = b1[j];
#pragma unroll
  for (int r = 0; r < 8; ++r)
    E1[(size_t)(a0 + r) * 512 + j] = fmaxf(acc[r] + bj, 0.f);
}

__global__ void out_kernel(const float* __restrict__ E1, const float* __restrict__ W2,
                           const float* __restrict__ b2, float* __restrict__ out) {
  int a = threadIdx.x;
  float a0 = 0.f, a1 = 0.f;
  const float* e = E1 + (size_t)a * 512;
  for (int k = 0; k < 512; ++k) {
    float v = e[k];
    a0 += v * W2[2 * k];
    a1 += v * W2[2 * k + 1];
  }
  out[2 * a] = a0 + b2[0];
  out[2 * a + 1] = a1 + b2[1];
}

// ---- host ---------------------------------------------------------------
extern "C" void kernel_launch(void* const* d_in, const int* in_sizes, int n_in,
                              void* d_out, int out_size, void* d_ws, size_t ws_size,
                              hipStream_t stream) {
  const int*   input1 = (const int*)d_in[0];
  const int*   input2 = (const int*)d_in[1];
  const int*   seql1  = (const int*)d_in[2];
  const int*   seql2  = (const int*)d_in[3];
  const float* emb    = (const float*)d_in[4];
  const float* lk     = (const float*)d_in[5];
  const float* lbias  = (const float*)d_in[6];
  const float* c1i    = (const float*)d_in[7];
  const float* h1i    = (const float*)d_in[8];
  const float* c2i    = (const float*)d_in[9];
  const float* h2i    = (const float*)d_in[10];
  const float* W_h    = (const float*)d_in[11];
  const float* W1     = (const float*)d_in[12];
  const float* b1     = (const float*)d_in[13];
  const float* W2     = (const float*)d_in[14];
  const float* b2     = (const float*)d_in[15];

  char* ws = (char*)d_ws;
  bf16*     WbT   = (bf16*)(ws + WBT_OFF);
  bf16*     Xb    = (bf16*)(ws + XB_OFF);
  bf16*     Hb    = (bf16*)(ws + HB_OFF);
  float*    biasp = (float*)(ws + BIASP_OFF);
  float*    HC    = (float*)(ws + HC_OFF);
  float*    H2T   = (float*)(ws + H2T_OFF);
  float*    T1    = (float*)(ws + T1_OFF);
  float*    E1    = (float*)(ws + E1_OFF);
  unsigned* bar   = (unsigned*)(ws + BAR_OFF);

  pack_wbt<<<dim3(16, 1344), 256, 0, stream>>>(lk, WbT);
  pack_xb<<<81920, 256, 0, stream>>>(input1, input2, emb, Xb);
  pack_misc<<<2048, 256, 0, stream>>>(h1i, h2i, lbias, Hb, biasp, bar);

  void* kargs[] = { (void*)&Xb, (void*)&WbT, (void*)&Hb, (void*)&biasp,
                    (void*)&c1i, (void*)&c2i, (void*)&seql1, (void*)&seql2,
                    (void*)&bar };
  hipLaunchCooperativeKernel((void*)lstm_coop, dim3(256), dim3(256), kargs, 0, stream);

  feat_kernel<<<256, 256, 0, stream>>>(Hb, seql1, seql2, HC, H2T);
  t1_kernel<<<dim3(5, 8), 256, 0, stream>>>(HC, W_h, T1);
  inter_kernel<<<32, 256, 0, stream>>>(T1, H2T, HC);
  e1_kernel<<<dim3(32, 2), 256, 0, stream>>>(HC, W1, b1, E1);
  out_kernel<<<1, 256, 0, stream>>>(E1, W2, b2, (float*)d_out);
}

// Round 9
// 3946.069 us; speedup vs baseline: 1.9495x; 1.9495x over previous
//
#include <hip/hip_runtime.h>
#include <hip/hip_bf16.h>

typedef __bf16 bf16;
typedef __bf16 bf16x8 __attribute__((ext_vector_type(8)));
typedef float f32x4 __attribute__((ext_vector_type(4)));

#define N_ROWS   512      // rows 0..255 seq1, 256..511 seq2
#define HID      1024
#define KX       320      // EMB=300 padded to 320
#define KTOT     1344     // 320 + 1024
#define NSTEPS   128
#define EMB_D    300
#define HC_W     3332     // 1025+1025+1+1025+256

// workspace layout (bytes)
#define WBT_OFF   0UL          // bf16 [4096][1344]  (packed, transposed)
#define XB_OFF    11010048UL   // bf16 [128][512][320]
#define HB_OFF    52953088UL   // bf16 [2][512][1024]
#define BIASP_OFF 55050240UL   // f32  [4096] (packed order)
#define HC_OFF    55066624UL   // f32  [256][3332]
#define H2T_OFF   58478592UL   // f32  [1025][256]
#define T1_OFF    59528192UL   // f32  [256][1025]
#define E1_OFF    60577792UL   // f32  [256][512]
// barrier region (dwords from BAR_OFF):
//   ga[g]   at dword g*16   (g=0..7)   8 monotonic arrive lines, 64B apart
//   gsum    at dword 128               monotonic summary line
//   flag[t] at dword 256 + t*16        per-step flag lines (fresh each step)
#define BAR_OFF   61102080UL

__device__ __forceinline__ float sigm(float x) { return 1.f / (1.f + __expf(-x)); }
__device__ __forceinline__ float tanh_fast(float x) {
  float xc = fminf(fmaxf(x, -15.f), 15.f);
  float e = __expf(2.f * xc);
  return (e - 1.f) / (e + 1.f);
}

// ---- pack kernels (r2-proven versions) ----------------------------------
// packed gate-col order: p = cbk*128 + g*32 + c  <->  orig col g*1024 + cbk*32 + c
__global__ void pack_wbt(const float* __restrict__ lk, bf16* __restrict__ wbt) {
  int p = blockIdx.x * 256 + threadIdx.x;   // 0..4095
  int k = blockIdx.y;                        // 0..1343
  int cbk = p >> 7, g = (p >> 5) & 3, c = p & 31;
  int oc = g * HID + cbk * 32 + c;
  float v = 0.f;
  if (k < KX) { if (k < EMB_D) v = lk[(size_t)k * 4096 + oc]; }
  else v = lk[(size_t)(EMB_D + k - KX) * 4096 + oc];
  wbt[(size_t)p * KTOT + k] = (bf16)v;
}

__global__ void pack_xb(const int* __restrict__ in1, const int* __restrict__ in2,
                        const float* __restrict__ emb, bf16* __restrict__ xb) {
  int idx = blockIdx.x * 256 + threadIdx.x;  // < 128*512*320
  int e = idx % 320;
  int rt = idx / 320;
  int r = rt & 511;
  int t = rt >> 9;
  int tok = (r < 256) ? in1[r * 128 + t] : in2[(r - 256) * 128 + t];
  float v = (e < EMB_D) ? emb[(size_t)tok * EMB_D + e] : 0.f;
  xb[(size_t)idx] = (bf16)v;
}

__global__ void pack_misc(const float* __restrict__ h1i, const float* __restrict__ h2i,
                          const float* __restrict__ bias, bf16* __restrict__ hb0,
                          float* __restrict__ biasp, unsigned* __restrict__ bar) {
  int idx = blockIdx.x * 256 + threadIdx.x;
  if (idx < N_ROWS * HID) {
    int r = idx >> 10, k = idx & 1023;
    float v = (r < 256) ? h1i[(size_t)r * HID + k] : h2i[(size_t)(r - 256) * HID + k];
    hb0[idx] = (bf16)v;
  }
  if (idx < 4096) {
    int cbk = idx >> 7, g = (idx >> 5) & 3, c = idx & 31;
    biasp[idx] = bias[g * HID + cbk * 32 + c];
    bar[idx] = 0u;   // reset all barrier lines (16 KB region) every launch
  }
}

// ---- cooperative LSTM recurrence ---------------------------------------
// grid 256 = 8 row-blocks x 32 cell-col-blocks (r6-proven mapping; under
// round-robin bid->XCD each XCD hosts 4 distinct cbk -> 1.4MB weight set,
// and the 8 sharers of a cbk slice are co-resident on one XCD).
// wave w owns rows w*16..w*16+15, ALL 128 packed cols (no gate exchange):
//   acc[ni][q] = G[row=w*16+(lane>>4)*4+q][pcol=ni*16+(lane&15)], g=ni>>1
// Double-buffered As/Bs, 1 __syncthreads/chunk; loads issued 2 chunks ahead.
// r9 barrier (vs r6): hierarchical single-acquire lockstep barrier.
//   arrive: RELEASE fetch_add on own group line (8 lines, 32 fan-in each,
//           no cache invalidate); 32nd arriver ACQUIRE-loads the line
//           (release-sequence), RELEASE-RMWs summary; 8th summary arriver
//           sets the per-step flag (fresh line per step).
//   wait (kc==3): relaxed-poll flag, then ONE acquire. One L2 inval per
//   block per step total (r6 did 2; r8's 8 caused the 4.8GB L2-fill blowup).
__launch_bounds__(256, 2)
__global__ void lstm_coop(const bf16* __restrict__ xb, const bf16* __restrict__ wbt,
                          bf16* __restrict__ hb, const float* __restrict__ biasp,
                          const float* __restrict__ c1i, const float* __restrict__ c2i,
                          const int* __restrict__ s1, const int* __restrict__ s2,
                          unsigned* __restrict__ bar) {
  __shared__ bf16 As[2][64][64];     // 16 KB, XOR-swizzled 16B chunks
  __shared__ bf16 Bs[2][128][64];    // 32 KB
  const int tid = threadIdx.x;
  const int wave = tid >> 6;
  const int lane = tid & 63;
  const int lrow = lane & 15;
  const int hi = lane >> 4;        // 0..3
  const int l7 = lane & 7;
  const int bid = blockIdx.x;
  const int rb = bid >> 5;
  const int cbk = bid & 31;
  const int r0 = rb * 64;

  const int rowbase = r0 + wave * 16 + hi * 4;   // + q (q=0..3)
  const int cell0 = cbk * 32 + lrow;             // + 16*e (e=0..1)

  int slen[4];
#pragma unroll
  for (int q = 0; q < 4; ++q) {
    int rr = rowbase + q;
    slen[q] = (rr < 256) ? s1[rr] : s2[rr - 256];
  }

  float creg[2][4];   // [e][q], stays f32 in registers
  {
    const float* cb = (rowbase < 256) ? c1i : c2i;
    const int radj = (rowbase < 256) ? rowbase : rowbase - 256;
#pragma unroll
    for (int e = 0; e < 2; ++e)
#pragma unroll
      for (int q = 0; q < 4; ++q)
        creg[e][q] = cb[(size_t)(radj + q) * HID + cell0 + e * 16];
  }

  // bias folded into accumulator init: acc[ni] col = ni*16+lrow (col-only dep)
  float bv[8];
#pragma unroll
  for (int ni = 0; ni < 8; ++ni)
    bv[ni] = biasp[cbk * 128 + ni * 16 + lrow];

  const bf16* wsrc = wbt + (size_t)(cbk * 128) * KTOT;

  // staging thread mapping (r2-proven swizzles)
  const int a_r = tid >> 2, a_c = tid & 3;
  const int b_r8 = tid >> 3, b_c = tid & 7;
  const int asw0 = ((a_c       ^ (a_r & 7)) << 3);
  const int asw1 = (((a_c + 4) ^ (a_r & 7)) << 3);
  const int bsw  = ((b_c ^ (b_r8 & 7)) << 3);     // +32q keeps row&7 constant

  bf16x8 ra0, ra1, rbv[4];
  auto issue_loads = [&](int nt, int nkc) {
    const bf16* asrc = (nkc < 5)
        ? (xb + ((size_t)nt * N_ROWS + r0 + a_r) * KX + nkc * 64 + a_c * 8)
        : (hb + ((size_t)(nt & 1) << 19) + ((size_t)(r0 + a_r) << 10) +
           (nkc * 64 - KX) + a_c * 8);
    ra0 = *reinterpret_cast<const bf16x8*>(asrc);
    ra1 = *reinterpret_cast<const bf16x8*>(asrc + 32);
    const bf16* bsrc = wsrc + (size_t)b_r8 * KTOT + nkc * 64 + b_c * 8;
#pragma unroll
    for (int q = 0; q < 4; ++q)
      rbv[q] = *reinterpret_cast<const bf16x8*>(bsrc + (size_t)(32 * q) * KTOT);
  };

  // prologue: buf0 <- chunk 0 (t=0, x); regs <- chunk 1
  issue_loads(0, 0);
  *reinterpret_cast<bf16x8*>(&As[0][a_r][asw0]) = ra0;
  *reinterpret_cast<bf16x8*>(&As[0][a_r][asw1]) = ra1;
#pragma unroll
  for (int q = 0; q < 4; ++q)
    *reinterpret_cast<bf16x8*>(&Bs[0][b_r8 + 32 * q][bsw]) = rbv[q];
  issue_loads(0, 1);
  __syncthreads();
  int db = 0;

  unsigned* ga    = bar + (bid & 7) * 16;   // own group arrive line (64B apart)
  unsigned* gsum  = bar + 128;              // summary line
  unsigned* flags = bar + 256;              // flag[t] at flags + t*16

  for (int t = 0; t < NSTEPS; ++t) {
    f32x4 acc[8];
#pragma unroll
    for (int ni = 0; ni < 8; ++ni)
      acc[ni] = f32x4{bv[ni], bv[ni], bv[ni], bv[ni]};

    for (int kc = 0; kc < 21; ++kc) {
      // stage chunk kc+1 (regs invariant) into the other buffer
      *reinterpret_cast<bf16x8*>(&As[db ^ 1][a_r][asw0]) = ra0;
      *reinterpret_cast<bf16x8*>(&As[db ^ 1][a_r][asw1]) = ra1;
#pragma unroll
      for (int q = 0; q < 4; ++q)
        *reinterpret_cast<bf16x8*>(&Bs[db ^ 1][b_r8 + 32 * q][bsw]) = rbv[q];

      // grid wait: peers' h(t) must be visible before the first h-load ISSUE
      // (nkc=5, issued this iteration). x-chunks 0..2 covered the latency.
      if (kc == 3 && t > 0) {
        if (tid == 0) {
          const unsigned* fl = flags + (t - 1) * 16;
          while (__hip_atomic_load(fl, __ATOMIC_RELAXED, __HIP_MEMORY_SCOPE_AGENT) == 0u)
            __builtin_amdgcn_s_sleep(2);
          (void)__hip_atomic_load(fl, __ATOMIC_ACQUIRE, __HIP_MEMORY_SCOPE_AGENT);
        }
        __syncthreads();
      }

      // issue loads for chunk kc+2 (wraps into next step's x-chunks)
      {
        int nkc = kc + 2, nt = t;
        if (nkc > 20) { nkc -= 21; ++nt; }
        if (nt < NSTEPS) issue_loads(nt, nkc);
      }

      // compute chunk kc from buf[db]
#pragma unroll
      for (int ks = 0; ks < 2; ++ks) {
        const int cs = (((ks << 2) | hi) ^ l7) << 3;
        bf16x8 af = *reinterpret_cast<const bf16x8*>(&As[db][wave * 16 + lrow][cs]);
#pragma unroll
        for (int ni = 0; ni < 8; ++ni) {
          bf16x8 bfv = *reinterpret_cast<const bf16x8*>(&Bs[db][ni * 16 + lrow][cs]);
          acc[ni] = __builtin_amdgcn_mfma_f32_16x16x32_bf16(af, bfv, acc[ni], 0, 0, 0);
        }
      }
      __syncthreads();
      db ^= 1;
    }

    // cell update: fully in-register (g = ni>>1, cc = (ni&1)*16 + lrow)
    {
      const size_t curo = (size_t)(t & 1) << 19;
      const bf16* hc = hb + curo;
      bf16* hnb = hb + (curo ^ ((size_t)1 << 19));
#pragma unroll
      for (int e = 0; e < 2; ++e)
#pragma unroll
        for (int q = 0; q < 4; ++q) {
          float ig = acc[0 + e][q];
          float jg = acc[2 + e][q];
          float fg = acc[4 + e][q];
          float og = acc[6 + e][q];
          float cn = sigm(fg + 1.f) * creg[e][q] + sigm(ig) * tanh_fast(jg);
          float hv = tanh_fast(cn) * sigm(og);
          size_t off = ((size_t)(rowbase + q) << 10) + cell0 + e * 16;
          float ho;
          if (t < slen[q]) { creg[e][q] = cn; ho = hv; }
          else ho = (float)hc[off];
          hnb[off] = (bf16)ho;
        }
    }

    // arrive: drain h stores (syncthreads emits vmcnt(0)), then hierarchical
    // release chain: ga (32 fan-in, RELEASE) -> gsum (8 fan-in) -> flag[t].
    __syncthreads();
    if (t < NSTEPS - 1 && tid == 0) {
      unsigned prev = __hip_atomic_fetch_add(ga, 1u, __ATOMIC_RELEASE,
                                             __HIP_MEMORY_SCOPE_AGENT);
      if ((prev & 31u) == 31u) {        // 32nd arrival of this step on this line
        (void)__hip_atomic_load(ga, __ATOMIC_ACQUIRE, __HIP_MEMORY_SCOPE_AGENT);
        unsigned p2 = __hip_atomic_fetch_add(gsum, 1u, __ATOMIC_RELEASE,
                                             __HIP_MEMORY_SCOPE_AGENT);
        if ((p2 & 7u) == 7u) {          // all 8 groups done
          (void)__hip_atomic_load(gsum, __ATOMIC_ACQUIRE, __HIP_MEMORY_SCOPE_AGENT);
          __hip_atomic_store(flags + t * 16, 1u, __ATOMIC_RELEASE,
                             __HIP_MEMORY_SCOPE_AGENT);
        }
      }
    }
  }
}

// ---- head ---------------------------------------------------------------
__global__ void feat_kernel(const bf16* __restrict__ hb0, const int* __restrict__ s1,
                            const int* __restrict__ s2, float* __restrict__ HC,
                            float* __restrict__ H2T) {
  int a = blockIdx.x;
  int tid = threadIdx.x;
  __shared__ float red[256];
  const bf16* h1r = hb0 + (size_t)a * HID;
  const bf16* h2r = hb0 + (size_t)(a + 256) * HID;
  float l1 = (float)s1[a] * (1.f / 128.f);
  float l2 = (float)s2[a] * (1.f / 128.f);
  float dacc = 0.f;
  for (int k = tid; k < 1025; k += 256) {
    float v1 = (k < HID) ? (float)h1r[k] : l1;
    float v2 = (k < HID) ? (float)h2r[k] : l2;
    HC[(size_t)a * HC_W + k] = v1;
    HC[(size_t)a * HC_W + 1025 + k] = v2;
    HC[(size_t)a * HC_W + 2051 + k] = v1 * v2;
    H2T[(size_t)k * 256 + a] = v2;
    float d = v1 - v2;
    dacc += d * d;
  }
  red[tid] = dacc;
  __syncthreads();
  for (int s = 128; s > 0; s >>= 1) {
    if (tid < s) red[tid] += red[tid + s];
    __syncthreads();
  }
  if (tid == 0) HC[(size_t)a * HC_W + 2050] = red[0];
}

__global__ void t1_kernel(const float* __restrict__ HC, const float* __restrict__ Wh,
                          float* __restrict__ T1) {
  int j = blockIdx.x * 256 + threadIdx.x;
  int a0 = blockIdx.y * 32;
  __shared__ float sh[32][64];
  float acc[32];
#pragma unroll
  for (int r = 0; r < 32; ++r) acc[r] = 0.f;
  for (int kc = 0; kc < 1025; kc += 64) {
    int kn = (1025 - kc < 64) ? (1025 - kc) : 64;
    for (int idx = threadIdx.x; idx < 2048; idx += 256) {
      int r = idx >> 6, kk = idx & 63;
      sh[r][kk] = (kk < kn) ? HC[(size_t)(a0 + r) * HC_W + kc + kk] : 0.f;
    }
    __syncthreads();
    if (j < 1025) {
      for (int kk = 0; kk < kn; ++kk) {
        float w = Wh[(size_t)(kc + kk) * 1025 + j];
#pragma unroll
        for (int r = 0; r < 32; ++r) acc[r] += sh[r][kk] * w;
      }
    }
    __syncthreads();
  }
  if (j < 1025) {
    for (int r = 0; r < 32; ++r) T1[(size_t)(a0 + r) * 1025 + j] = acc[r];
  }
}

__global__ void inter_kernel(const float* __restrict__ T1, const float* __restrict__ H2T,
                             float* __restrict__ HC) {
  int a0 = blockIdx.x * 8;
  int b = threadIdx.x;
  __shared__ float sT[8][1025];
  for (int idx = threadIdx.x; idx < 8 * 1025; idx += 256) {
    int r = idx / 1025, k = idx - r * 1025;
    sT[r][k] = T1[(size_t)(a0 + r) * 1025 + k];
  }
  __syncthreads();
  float acc[8];
#pragma unroll
  for (int r = 0; r < 8; ++r) acc[r] = 0.f;
  for (int k = 0; k < 1025; ++k) {
    float v = H2T[(size_t)k * 256 + b];
#pragma unroll
    for (int r = 0; r < 8; ++r) acc[r] += sT[r][k] * v;
  }
#pragma unroll
  for (int r = 0; r < 8; ++r)
    HC[(size_t)(a0 + r) * HC_W + 3076 + b] = acc[r];
}

__global__ void e1_kernel(const float* __restrict__ HC, const float* __restrict__ W1,
                          const float* __restrict__ b1, float* __restrict__ E1) {
  int a0 = blockIdx.x * 8;
  int j = blockIdx.y * 256 + threadIdx.x;
  __shared__ float sh[8][128];
  float acc[8];
#pragma unroll
  for (int r = 0; r < 8; ++r) acc[r] = 0.f;
  for (int kc = 0; kc < HC_W; kc += 128) {
    int kn = (HC_W - kc < 128) ? (HC_W - kc) : 128;
    for (int idx = threadIdx.x; idx < 1024; idx += 256) {
      int r = idx >> 7, kk = idx & 127;
      sh[r][kk] = (kk < kn) ? HC[(size_t)(a0 + r) * HC_W + kc + kk] : 0.f;
    }
    __syncthreads();
    for (int kk = 0; kk < kn; ++kk) {
      float w = W1[(size_t)(kc + kk) * 512 + j];
#pragma unroll
      for (int r = 0; r < 8; ++r) acc[r] += sh[r][kk] * w;
    }
    __syncthreads();
  }
  float bj = b1[j];
#pragma unroll
  for (int r = 0; r < 8; ++r)
    E1[(size_t)(a0 + r) * 512 + j] = fmaxf(acc[r] + bj, 0.f);
}

__global__ void out_kernel(const float* __restrict__ E1, const float* __restrict__ W2,
                           const float* __restrict__ b2, float* __restrict__ out) {
  int a = threadIdx.x;
  float a0 = 0.f, a1 = 0.f;
  const float* e = E1 + (size_t)a * 512;
  for (int k = 0; k < 512; ++k) {
    float v = e[k];
    a0 += v * W2[2 * k];
    a1 += v * W2[2 * k + 1];
  }
  out[2 * a] = a0 + b2[0];
  out[2 * a + 1] = a1 + b2[1];
}

// ---- host ---------------------------------------------------------------
extern "C" void kernel_launch(void* const* d_in, const int* in_sizes, int n_in,
                              void* d_out, int out_size, void* d_ws, size_t ws_size,
                              hipStream_t stream) {
  const int*   input1 = (const int*)d_in[0];
  const int*   input2 = (const int*)d_in[1];
  const int*   seql1  = (const int*)d_in[2];
  const int*   seql2  = (const int*)d_in[3];
  const float* emb    = (const float*)d_in[4];
  const float* lk     = (const float*)d_in[5];
  const float* lbias  = (const float*)d_in[6];
  const float* c1i    = (const float*)d_in[7];
  const float* h1i    = (const float*)d_in[8];
  const float* c2i    = (const float*)d_in[9];
  const float* h2i    = (const float*)d_in[10];
  const float* W_h    = (const float*)d_in[11];
  const float* W1     = (const float*)d_in[12];
  const float* b1     = (const float*)d_in[13];
  const float* W2     = (const float*)d_in[14];
  const float* b2     = (const float*)d_in[15];

  char* ws = (char*)d_ws;
  bf16*     WbT   = (bf16*)(ws + WBT_OFF);
  bf16*     Xb    = (bf16*)(ws + XB_OFF);
  bf16*     Hb    = (bf16*)(ws + HB_OFF);
  float*    biasp = (float*)(ws + BIASP_OFF);
  float*    HC    = (float*)(ws + HC_OFF);
  float*    H2T   = (float*)(ws + H2T_OFF);
  float*    T1    = (float*)(ws + T1_OFF);
  float*    E1    = (float*)(ws + E1_OFF);
  unsigned* bar   = (unsigned*)(ws + BAR_OFF);

  pack_wbt<<<dim3(16, 1344), 256, 0, stream>>>(lk, WbT);
  pack_xb<<<81920, 256, 0, stream>>>(input1, input2, emb, Xb);
  pack_misc<<<2048, 256, 0, stream>>>(h1i, h2i, lbias, Hb, biasp, bar);

  void* kargs[] = { (void*)&Xb, (void*)&WbT, (void*)&Hb, (void*)&biasp,
                    (void*)&c1i, (void*)&c2i, (void*)&seql1, (void*)&seql2,
                    (void*)&bar };
  hipLaunchCooperativeKernel((void*)lstm_coop, dim3(256), dim3(256), kargs, 0, stream);

  feat_kernel<<<256, 256, 0, stream>>>(Hb, seql1, seql2, HC, H2T);
  t1_kernel<<<dim3(5, 8), 256, 0, stream>>>(HC, W_h, T1);
  inter_kernel<<<32, 256, 0, stream>>>(T1, H2T, HC);
  e1_kernel<<<dim3(32, 2), 256, 0, stream>>>(HC, W1, b1, E1);
  out_kernel<<<1, 256, 0, stream>>>(E1, W2, b2, (float*)d_out);
}